// Round 11
// baseline (114.382 us; speedup 1.0000x reference)
//
#include <hip/hip_runtime.h>
#include <cstdint>
#include <cstddef>

#define N_SEQ 4096
#define D_HEAD 128
#define KP_DIM 256

typedef __attribute__((ext_vector_type(4))) float f32x4;
typedef __attribute__((ext_vector_type(8))) short bf16x8;
typedef __attribute__((ext_vector_type(4))) short s16x4;
typedef __attribute__((ext_vector_type(2))) unsigned int u32x2;

static __device__ __forceinline__ short f2bf(float f) {
  uint32_t u = __builtin_bit_cast(uint32_t, f);
  u += 0x7FFFu + ((u >> 16) & 1u);
  return (short)(u >> 16);
}

static __device__ __forceinline__ unsigned int cvtpk(float a, float b) {
  unsigned int r;
  asm("v_cvt_pk_bf16_f32 %0, %1, %2" : "=v"(r) : "v"(a), "v"(b));
  return r;
}

static __device__ __forceinline__ int swz8(int r) { return (r ^ (r >> 2)) & 7; }

// ---------------------------------------------------------------------------
// Stage 0: convert E_W,F_W f32 -> bf16 wbf[2][256][4096] (d_out scratch)
// ---------------------------------------------------------------------------
__global__ __launch_bounds__(256) void conv_w_kernel(
    const float* __restrict__ EW, const float* __restrict__ FW,
    short* __restrict__ wbf) {
  const int idx = blockIdx.x * 256 + threadIdx.x;
  const int half = 262144;
  f32x4 v = (idx < half) ? *(const f32x4*)(EW + (size_t)idx * 4)
                         : *(const f32x4*)(FW + (size_t)(idx - half) * 4);
  u32x2 h = {cvtpk(v[0], v[1]), cvtpk(v[2], v[3])};
  *(u32x2*)(wbf + (size_t)idx * 4) = h;
}

// ---------------------------------------------------------------------------
// Stage 1 (v5): partial projections, W direct from L2 (no W LDS staging).
// grid 512 (XCD-chunked: each XCD one (p,s) -> W slice 512KB L2-resident;
// both kh blocks of a (b,p,s) co-XCD -> X chunk L2-shared), 512 thr = 8 waves.
// Block = (b,p,s,kh): out rows k in [kh*128,+128), all 128 d, n-chunk s*1024.
// Waves 4k x 2d -> 32k x 64d tiles, acc 2x4 (32 VGPR). LDS = X^T tile only,
// 2 x 16KB double-buffered -> 2 blocks/CU (4 waves/SIMD).
// pws[b][p][s][k 256][d 128] f32 partials (in d_out+8MB).
// ---------------------------------------------------------------------------
__global__ __launch_bounds__(512, 4) void proj_partial_kernel(
    const float* __restrict__ Kin, const float* __restrict__ Vin,
    const short* __restrict__ wbf, float* __restrict__ pws) {
  const int bid = blockIdx.x;                  // 0..511
  const int wk = (bid & 7) * 64 + (bid >> 3);  // XCD x owns wk [64x, 64x+64)
  const int kh = wk & 1;
  const int b = (wk >> 1) & 31;
  const int s = (wk >> 6) & 3;
  const int p = wk >> 8;

  const float* __restrict__ X = (p == 0 ? Kin : Vin) + (size_t)b * (N_SEQ * D_HEAD);
  const short* __restrict__ wp =
      wbf + (size_t)p * (KP_DIM * N_SEQ) + (size_t)(kh * 128) * N_SEQ;
  float* __restrict__ outp = pws + ((((size_t)b * 2 + p) * 4) + s) * (KP_DIM * D_HEAD)
                             + (size_t)(kh * 128) * D_HEAD;

  __shared__ __align__(16) short xt[2][D_HEAD * 64];  // 16KB x2: X^T [128 d][64 n]

  const int t = threadIdx.x;
  const int lane = t & 63;
  const int w = t >> 6;            // 0..7
  const int wkk = (w >> 1) * 32;   // k offset of wave (4 groups of 32)
  const int wdd = (w & 1) * 64;    // d offset of wave (2 groups of 64)
  const int l15 = lane & 15;
  const int l4 = lane >> 4;
  const int dq = t & 31;           // d-quad for X staging
  const int ng = t >> 5;           // n-group 0..15 for X staging

  const int n0 = s * 1024;

  f32x4 acc[2][4];
#pragma unroll
  for (int i = 0; i < 2; ++i)
#pragma unroll
    for (int j = 0; j < 4; ++j) acc[i][j] = (f32x4){0.f, 0.f, 0.f, 0.f};

  f32x4 xreg[4];

  // ---- prologue: stage X tile 0 ----
#pragma unroll
  for (int i = 0; i < 4; ++i)
    xreg[i] = *(const f32x4*)(X + (size_t)(n0 + ng * 4 + i) * D_HEAD + dq * 4);
  asm volatile("s_waitcnt vmcnt(0)" ::: "memory");
#pragma unroll
  for (int j = 0; j < 4; ++j) {
    int drow = dq * 4 + j;
    u32x2 hv = {cvtpk(xreg[0][j], xreg[1][j]), cvtpk(xreg[2][j], xreg[3][j])};
    *(u32x2*)(&xt[0][drow * 64 + ((ng * 4) ^ (swz8(drow) << 3))]) = hv;
  }
  __syncthreads();

  // ---- main loop: 16 iters of BK=64, X double-buffered, W from L2 ----
  for (int it = 0; it < 16; ++it) {
    const int cur = it & 1, nxt = cur ^ 1;
    const int nn = n0 + it * 64;
    if (it < 15) {
      const int nc = nn + 64;
#pragma unroll
      for (int i = 0; i < 4; ++i)
        xreg[i] = *(const f32x4*)(X + (size_t)(nc + ng * 4 + i) * D_HEAD + dq * 4);
    }
    // ---- compute: a-frags direct from global (L2), bb from LDS ----
#pragma unroll
    for (int ks2 = 0; ks2 < 2; ++ks2) {
      const int col0 = ks2 * 32 + l4 * 8;
      bf16x8 a[2], bb[4];
#pragma unroll
      for (int mt = 0; mt < 2; ++mt) {
        int kr = wkk + mt * 16 + l15;
        a[mt] = *(const bf16x8*)(wp + (size_t)kr * N_SEQ + nn + col0);
      }
#pragma unroll
      for (int nt = 0; nt < 4; ++nt) {
        int row = wdd + nt * 16 + l15;
        bb[nt] = *(const bf16x8*)(&xt[cur][row * 64 + (col0 ^ (swz8(row) << 3))]);
      }
#pragma unroll
      for (int mt = 0; mt < 2; ++mt)
#pragma unroll
        for (int nt = 0; nt < 4; ++nt)
          acc[mt][nt] = __builtin_amdgcn_mfma_f32_16x16x32_bf16(a[mt], bb[nt], acc[mt][nt], 0, 0, 0);
    }
    if (it < 15) {
      asm volatile("s_waitcnt vmcnt(0)" ::: "memory");
#pragma unroll
      for (int j = 0; j < 4; ++j) {
        int drow = dq * 4 + j;
        u32x2 hv = {cvtpk(xreg[0][j], xreg[1][j]), cvtpk(xreg[2][j], xreg[3][j])};
        *(u32x2*)(&xt[nxt][drow * 64 + ((ng * 4) ^ (swz8(drow) << 3))]) = hv;
      }
    }
    __syncthreads();
  }

  // ---- write f32 partials ----
#pragma unroll
  for (int mt = 0; mt < 2; ++mt)
#pragma unroll
    for (int nt = 0; nt < 4; ++nt)
#pragma unroll
      for (int r = 0; r < 4; ++r) {
        int kk = wkk + mt * 16 + l4 * 4 + r;
        int dd = wdd + nt * 16 + l15;
        outp[kk * D_HEAD + dd] = acc[mt][nt][r];
      }
}

// ---------------------------------------------------------------------------
// Stage 1b: reduce 4 partials + bias. grid 128 (unchanged).
// ---------------------------------------------------------------------------
__global__ __launch_bounds__(256) void reduce_bias_kernel(
    const float* __restrict__ pws, const float* __restrict__ Eb,
    const float* __restrict__ Fb, short* __restrict__ kp, short* __restrict__ vpt) {
  const int sub = blockIdx.x & 3;
  const int b = blockIdx.x >> 2;
  const int t = threadIdx.x;
  __shared__ short tile[128 * 128];
  if (sub < 2) {
    const float* __restrict__ base = pws + ((size_t)b * 2) * 4 * 32768;
    const int off = sub * 16384;
    for (int i = t; i < 16384; i += 256) {
      int ii = off + i;
      int k = ii >> 7;
      float v = base[ii] + base[ii + 32768] + base[ii + 65536] + base[ii + 98304] + Eb[k];
      kp[(size_t)b * 32768 + ii] = f2bf(v);
    }
  } else {
    const int kh = sub - 2;
    const float* __restrict__ base = pws + (((size_t)b * 2 + 1) * 4) * 32768 + kh * 16384;
    for (int i = t; i < 16384; i += 256) {
      int kl = i >> 7, d = i & 127;
      float v = base[i] + base[i + 32768] + base[i + 65536] + base[i + 98304] + Fb[kh * 128 + kl];
      tile[kl * 128 + (d ^ ((kl & 15) << 3))] = f2bf(v);
    }
    __syncthreads();
    for (int i = t; i < 16384; i += 256) {
      int d = i >> 7, kl = i & 127;
      vpt[(size_t)b * 32768 + d * 256 + kh * 128 + kl] = tile[kl * 128 + (d ^ ((kl & 15) << 3))];
    }
  }
}

// ---------------------------------------------------------------------------
// Stage 2: attention v4 (unchanged, verified). grid 256, 1024 thr,
// __launch_bounds__(1024,4), 160KB LDS, zero mid-loop barriers.
// ---------------------------------------------------------------------------
__global__ __launch_bounds__(1024, 4) void attn_kernel(
    const float* __restrict__ Q, const short* __restrict__ kp,
    const short* __restrict__ vpt, float* __restrict__ out) {
  const int bid = blockIdx.x;
  const int wk = (bid & 7) * 32 + (bid >> 3);  // XCD-chunked: 4 b's per XCD
  const int b = wk >> 3;
  const int slice = wk & 7;
  const int t = threadIdx.x;
  const int lane = t & 63;
  const int w = t >> 6;  // 0..15
  const int l15 = lane & 15, l4 = lane >> 4;

  __shared__ __align__(16) short lbuf[81920];
  short* lkp = lbuf;
  short* lvpt = lbuf + 32768;
  short* lpw = lbuf + 65536 + w * 1024;  // 2KB/wave

  const short* __restrict__ kpb = kp + (size_t)b * 32768;
  const short* __restrict__ vptb = vpt + (size_t)b * 32768;

#pragma unroll
  for (int i = 0; i < 4; ++i) {
    int g = t + i * 1024;
    int row = g >> 4, c = g & 15;
    __builtin_amdgcn_global_load_lds(
        (const __attribute__((address_space(1))) void*)(kpb + (size_t)row * 128 +
                                                        ((c ^ (row & 7)) << 3)),
        (__attribute__((address_space(3))) void*)(&lkp[g * 8]), 16, 0, 0);
  }
#pragma unroll
  for (int i = 0; i < 4; ++i) {
    int g = t + i * 1024;
    int row = g >> 5, c = g & 31;
    __builtin_amdgcn_global_load_lds(
        (const __attribute__((address_space(1))) void*)(vptb + (size_t)row * 256 +
                                                        ((c ^ (row & 7)) << 3)),
        (__attribute__((address_space(3))) void*)(&lvpt[g * 8]), 16, 0, 0);
  }

  const float scale = 0.08838834764831845f;  // 1/sqrt(128)
  f32x4 qraw[8];
  {
    const float* qr = Q + ((size_t)b * N_SEQ + slice * 512 + w * 16 + l15) * D_HEAD;
#pragma unroll
    for (int ks = 0; ks < 4; ++ks) {
      qraw[2 * ks] = *(const f32x4*)(qr + ks * 32 + l4 * 8);
      qraw[2 * ks + 1] = *(const f32x4*)(qr + ks * 32 + l4 * 8 + 4);
    }
  }
  asm volatile("s_waitcnt vmcnt(0)" ::: "memory");
  __syncthreads();

#pragma unroll
  for (int rd = 0; rd < 2; ++rd) {
    const int rowBase = slice * 512 + rd * 256 + w * 16;

    bf16x8 qf[4];
#pragma unroll
    for (int ks = 0; ks < 4; ++ks) {
      union { unsigned int u[4]; bf16x8 v; } cv;
      cv.u[0] = cvtpk(qraw[2 * ks][0] * scale, qraw[2 * ks][1] * scale);
      cv.u[1] = cvtpk(qraw[2 * ks][2] * scale, qraw[2 * ks][3] * scale);
      cv.u[2] = cvtpk(qraw[2 * ks + 1][0] * scale, qraw[2 * ks + 1][1] * scale);
      cv.u[3] = cvtpk(qraw[2 * ks + 1][2] * scale, qraw[2 * ks + 1][3] * scale);
      qf[ks] = cv.v;
    }

    f32x4 accs[16];
#pragma unroll
    for (int i = 0; i < 16; ++i) accs[i] = (f32x4){0.f, 0.f, 0.f, 0.f};
#pragma unroll
    for (int ks = 0; ks < 4; ++ks) {
#pragma unroll
      for (int nt = 0; nt < 16; ++nt) {
        bf16x8 af = *(const bf16x8*)(&lkp[(nt * 16 + l15) * 128 +
                                          (((ks * 4 + l4) ^ (l15 & 7)) << 3)]);
        accs[nt] = __builtin_amdgcn_mfma_f32_16x16x32_bf16(af, qf[ks], accs[nt], 0, 0, 0);
      }
    }

    float m = -1e30f;
#pragma unroll
    for (int nt = 0; nt < 16; ++nt)
#pragma unroll
      for (int r = 0; r < 4; ++r) m = fmaxf(m, accs[nt][r]);
    m = fmaxf(m, __shfl_xor(m, 16));
    m = fmaxf(m, __shfl_xor(m, 32));
    float s = 0.f;
#pragma unroll
    for (int nt = 0; nt < 16; ++nt)
#pragma unroll
      for (int r = 0; r < 4; ++r) {
        float e = __expf(accs[nt][r] - m);
        accs[nt][r] = e;
        s += e;
      }
    s += __shfl_xor(s, 16);
    s += __shfl_xor(s, 32);
    float inv = 1.0f / s;

    f32x4 acco[8];
#pragma unroll
    for (int i = 0; i < 8; ++i) acco[i] = (f32x4){0.f, 0.f, 0.f, 0.f};
#pragma unroll
    for (int qq = 0; qq < 4; ++qq) {
#pragma unroll
      for (int ntl = 0; ntl < 4; ++ntl) {
        int nt = qq * 4 + ntl;
        int cw = 2 * ntl + (l4 >> 1);
        unsigned int p0 = cvtpk(accs[nt][0] * inv, accs[nt][1] * inv);
        unsigned int p1 = cvtpk(accs[nt][2] * inv, accs[nt][3] * inv);
        *(u32x2*)((char*)lpw + l15 * 128 + ((cw ^ (l15 & 7)) << 4) + (l4 & 1) * 8) =
            (u32x2){p0, p1};
      }
      if (rd == 0 && qq == 3) {
        const float* qr = Q + ((size_t)b * N_SEQ + slice * 512 + 256 + w * 16 + l15) * D_HEAD;
#pragma unroll
        for (int ks = 0; ks < 4; ++ks) {
          qraw[2 * ks] = *(const f32x4*)(qr + ks * 32 + l4 * 8);
          qraw[2 * ks + 1] = *(const f32x4*)(qr + ks * 32 + l4 * 8 + 4);
        }
      }
#pragma unroll
      for (int ksl = 0; ksl < 2; ++ksl) {
        bf16x8 pa = *(const bf16x8*)((char*)lpw + l15 * 128 +
                                     (((4 * ksl + l4) ^ (l15 & 7)) << 4));
        int ksa = qq * 2 + ksl;
#pragma unroll
        for (int ntv = 0; ntv < 8; ++ntv) {
          bf16x8 av = *(const bf16x8*)(&lvpt[(ntv * 16 + l15) * 256 +
                                             (((ksa * 4 + l4) ^ (l15 & 7)) << 3)]);
          acco[ntv] = __builtin_amdgcn_mfma_f32_16x16x32_bf16(av, pa, acco[ntv], 0, 0, 0);
        }
      }
    }

    float* ob = out + ((size_t)b * N_SEQ + rowBase) * D_HEAD;
#pragma unroll
    for (int ntv = 0; ntv < 8; ++ntv)
      *(f32x4*)(ob + (size_t)l15 * D_HEAD + ntv * 16 + l4 * 4) = acco[ntv];
  }
}

// ---------------------------------------------------------------------------
extern "C" void kernel_launch(void* const* d_in, const int* in_sizes, int n_in,
                              void* d_out, int out_size, void* d_ws, size_t ws_size,
                              hipStream_t stream) {
  const float* Q  = (const float*)d_in[0];
  const float* K  = (const float*)d_in[1];
  const float* V  = (const float*)d_in[2];
  const float* EW = (const float*)d_in[3];
  const float* Eb = (const float*)d_in[4];
  const float* FW = (const float*)d_in[5];
  const float* Fb = (const float*)d_in[6];
  float* out = (float*)d_out;

  // d_out scratch (dead before attn writes): [0,4MB) wbf; [8MB,41.5MB) pws
  short* wbf = (short*)d_out;
  float* pws = (float*)d_out + 2097152;
  short* kpb = (short*)d_ws;
  short* vpt = (short*)((char*)d_ws + (size_t)32 * KP_DIM * D_HEAD * 2);

  conv_w_kernel<<<dim3(2048), dim3(256), 0, stream>>>(EW, FW, wbf);
  proj_partial_kernel<<<dim3(512), dim3(512), 0, stream>>>(K, V, wbf, pws);
  reduce_bias_kernel<<<dim3(128), dim3(256), 0, stream>>>(pws, Eb, Fb, kpb, vpt);
  attn_kernel<<<dim3(256), dim3(1024), 0, stream>>>(Q, kpb, vpt, out);
}

// Round 12
// 100.001 us; speedup vs baseline: 1.1438x; 1.1438x over previous
//
#include <hip/hip_runtime.h>
#include <cstdint>
#include <cstddef>

#define N_SEQ 4096
#define D_HEAD 128
#define KP_DIM 256

typedef __attribute__((ext_vector_type(4))) float f32x4;
typedef __attribute__((ext_vector_type(8))) short bf16x8;
typedef __attribute__((ext_vector_type(4))) short s16x4;
typedef __attribute__((ext_vector_type(2))) unsigned int u32x2;

static __device__ __forceinline__ short f2bf(float f) {
  uint32_t u = __builtin_bit_cast(uint32_t, f);
  u += 0x7FFFu + ((u >> 16) & 1u);
  return (short)(u >> 16);
}

static __device__ __forceinline__ unsigned int cvtpk(float a, float b) {
  unsigned int r;
  asm("v_cvt_pk_bf16_f32 %0, %1, %2" : "=v"(r) : "v"(a), "v"(b));
  return r;
}

static __device__ __forceinline__ int swz8(int r) { return (r ^ (r >> 2)) & 7; }

// ---------------------------------------------------------------------------
// Stage 0: convert E_W,F_W f32 -> bf16 wbf[2][256][4096] (d_out scratch)
// ---------------------------------------------------------------------------
__global__ __launch_bounds__(256) void conv_w_kernel(
    const float* __restrict__ EW, const float* __restrict__ FW,
    short* __restrict__ wbf) {
  const int idx = blockIdx.x * 256 + threadIdx.x;
  const int half = 262144;
  f32x4 v = (idx < half) ? *(const f32x4*)(EW + (size_t)idx * 4)
                         : *(const f32x4*)(FW + (size_t)(idx - half) * 4);
  u32x2 h = {cvtpk(v[0], v[1]), cvtpk(v[2], v[3])};
  *(u32x2*)(wbf + (size_t)idx * 4) = h;
}

// ---------------------------------------------------------------------------
// Stage 1 (v6): partial projections. grid 512 (XCD-chunked), 512 thr = 8 waves
// (4k x 2d of 32x64). Block = (b,p,s,kh): out k in [kh*128,+128), all 128 d,
// n-chunk s*1024 (16 iters of BK=64). LDS 64KB (W 2x16K + X^T 2x16K) ->
// 2 blocks/CU (4 waves/SIMD). W staged via global_load_lds from bf16 wbf
// (pre-swizzled source); X depth-2 register prefetch, cvt_pk, reg-transpose.
// Counted vmcnt: main loop NEVER drains to 0 for X (depth-2 stays in flight).
// pws[b][p][s][k 256][d 128] f32 partials.
// ---------------------------------------------------------------------------
__global__ __launch_bounds__(512, 4) void proj_partial_kernel(
    const float* __restrict__ Kin, const float* __restrict__ Vin,
    const short* __restrict__ wbf, float* __restrict__ pws) {
  const int bid = blockIdx.x;                  // 0..511
  const int wk = (bid & 7) * 64 + (bid >> 3);  // XCD x owns wk [64x, 64x+64)
  const int kh = wk & 1;                       // kh pair same XCD -> X L2-shared
  const int b = (wk >> 1) & 31;
  const int s = (wk >> 6) & 3;
  const int p = wk >> 8;

  const float* __restrict__ X = (p == 0 ? Kin : Vin) + (size_t)b * (N_SEQ * D_HEAD);
  const short* __restrict__ wp =
      wbf + (size_t)p * (KP_DIM * N_SEQ) + (size_t)(kh * 128) * N_SEQ;
  float* __restrict__ outp = pws + ((((size_t)b * 2 + p) * 4) + s) * (KP_DIM * D_HEAD)
                             + (size_t)(kh * 128) * D_HEAD;

  __shared__ __align__(16) short lw[2][128 * 64];  // 16KB x2: W tile [128 k][64 n]
  __shared__ __align__(16) short xt[2][128 * 64];  // 16KB x2: X^T tile [128 d][64 n]

  const int t = threadIdx.x;
  const int lane = t & 63;
  const int w = t >> 6;            // 0..7
  const int wkk = (w >> 1) * 32;   // wave k offset (4 groups of 32)
  const int wdd = (w & 1) * 64;    // wave d offset (2 groups of 64)
  const int l15 = lane & 15;
  const int l4 = lane >> 4;
  const int dq = t & 31;           // d-quad for X staging
  const int ng = t >> 5;           // n-group 0..15 for X staging

  const int n0 = s * 1024;

  f32x4 acc[2][4];
#pragma unroll
  for (int i = 0; i < 2; ++i)
#pragma unroll
    for (int j = 0; j < 4; ++j) acc[i][j] = (f32x4){0.f, 0.f, 0.f, 0.f};

  f32x4 xA[4], xB[4];  // depth-2 X prefetch: even tiles -> xA, odd -> xB

#define PROJ_WISSUE(BUF, NC)                                                        \
  do {                                                                              \
    _Pragma("unroll") for (int i_ = 0; i_ < 2; ++i_) {                              \
      int g_ = t + i_ * 512;                                                        \
      int row_ = g_ >> 3, c_ = g_ & 7;                                              \
      __builtin_amdgcn_global_load_lds(                                             \
          (const __attribute__((address_space(1))) void*)(wp + (size_t)row_ * N_SEQ \
              + (NC) + ((c_ ^ swz8(row_)) << 3)),                                   \
          (__attribute__((address_space(3))) void*)(&lw[BUF][g_ * 8]), 16, 0, 0);   \
    }                                                                               \
  } while (0)

#define PROJ_XISSUE(XR, NC)                                                         \
  do {                                                                              \
    _Pragma("unroll") for (int i_ = 0; i_ < 4; ++i_)                                \
      XR[i_] = *(const f32x4*)(X + (size_t)((NC) + ng * 4 + i_) * D_HEAD + dq * 4); \
  } while (0)

#define PROJ_XCVT(XR, BUF)                                                          \
  do {                                                                              \
    _Pragma("unroll") for (int j_ = 0; j_ < 4; ++j_) {                              \
      int drow_ = dq * 4 + j_;                                                      \
      u32x2 hv_ = {cvtpk(XR[0][j_], XR[1][j_]), cvtpk(XR[2][j_], XR[3][j_])};       \
      *(u32x2*)(&xt[BUF][drow_ * 64 + ((ng * 4) ^ (swz8(drow_) << 3))]) = hv_;      \
    }                                                                               \
  } while (0)

#define PROJ_COMPUTE(CUR)                                                           \
  do {                                                                              \
    _Pragma("unroll") for (int ks2 = 0; ks2 < 2; ++ks2) {                           \
      const int col0 = ks2 * 32 + l4 * 8;                                           \
      bf16x8 a_[2], bb_[4];                                                         \
      _Pragma("unroll") for (int mt = 0; mt < 2; ++mt) {                            \
        int row_ = wkk + mt * 16 + l15;                                             \
        a_[mt] = *(const bf16x8*)(&lw[CUR][row_ * 64 + (col0 ^ (swz8(row_) << 3))]); \
      }                                                                             \
      _Pragma("unroll") for (int nt = 0; nt < 4; ++nt) {                            \
        int row_ = wdd + nt * 16 + l15;                                             \
        bb_[nt] = *(const bf16x8*)(&xt[CUR][row_ * 64 + (col0 ^ (swz8(row_) << 3))]); \
      }                                                                             \
      _Pragma("unroll") for (int mt = 0; mt < 2; ++mt)                              \
        _Pragma("unroll") for (int nt = 0; nt < 4; ++nt)                            \
          acc[mt][nt] = __builtin_amdgcn_mfma_f32_16x16x32_bf16(a_[mt], bb_[nt],    \
                                                                acc[mt][nt], 0, 0, 0); \
    }                                                                               \
  } while (0)

  // ---- prologue ----
  PROJ_XISSUE(xA, n0);                                   // X(0)
  PROJ_WISSUE(0, n0);                                    // W(0)
  asm volatile("s_waitcnt vmcnt(2)" ::: "memory");       // X(0) done
  PROJ_XCVT(xA, 0);
  PROJ_XISSUE(xB, n0 + 64);                              // X(1)
  asm volatile("s_waitcnt vmcnt(4)" ::: "memory");       // W(0) done, X(1) flies
  __syncthreads();

  // ---- main loop: iters 0..13 as 7 even/odd pairs ----
  for (int itp = 0; itp < 7; ++itp) {
    const int it0 = itp * 2;
    // even iter (cur=0)
    PROJ_WISSUE(1, n0 + (it0 + 1) * 64);                 // W(it+1)
    PROJ_XISSUE(xA, n0 + (it0 + 2) * 64);                // X(it+2)
    PROJ_COMPUTE(0);
    asm volatile("s_waitcnt vmcnt(6)" ::: "memory");     // X(it+1) done
    PROJ_XCVT(xB, 1);
    asm volatile("s_waitcnt vmcnt(4)" ::: "memory");     // W(it+1) done
    __syncthreads();
    // odd iter (cur=1)
    PROJ_WISSUE(0, n0 + (it0 + 2) * 64);
    PROJ_XISSUE(xB, n0 + (it0 + 3) * 64);
    PROJ_COMPUTE(1);
    asm volatile("s_waitcnt vmcnt(6)" ::: "memory");
    PROJ_XCVT(xA, 0);
    asm volatile("s_waitcnt vmcnt(4)" ::: "memory");
    __syncthreads();
  }
  // ---- it=14 (cur=0): last prefetches ----
  PROJ_WISSUE(1, n0 + 15 * 64);                          // W(15)
  PROJ_COMPUTE(0);
  asm volatile("s_waitcnt vmcnt(2)" ::: "memory");       // X(15) done
  PROJ_XCVT(xB, 1);
  asm volatile("s_waitcnt vmcnt(0)" ::: "memory");       // W(15) done
  __syncthreads();
  // ---- it=15 (cur=1) ----
  PROJ_COMPUTE(1);

#undef PROJ_WISSUE
#undef PROJ_XISSUE
#undef PROJ_XCVT
#undef PROJ_COMPUTE

  // ---- write f32 partials ----
#pragma unroll
  for (int mt = 0; mt < 2; ++mt)
#pragma unroll
    for (int nt = 0; nt < 4; ++nt)
#pragma unroll
      for (int r = 0; r < 4; ++r) {
        int kk = wkk + mt * 16 + l4 * 4 + r;
        int dd = wdd + nt * 16 + l15;
        outp[kk * D_HEAD + dd] = acc[mt][nt][r];
      }
}

// ---------------------------------------------------------------------------
// Stage 1b: reduce 4 partials + bias. grid 128 (unchanged).
// ---------------------------------------------------------------------------
__global__ __launch_bounds__(256) void reduce_bias_kernel(
    const float* __restrict__ pws, const float* __restrict__ Eb,
    const float* __restrict__ Fb, short* __restrict__ kp, short* __restrict__ vpt) {
  const int sub = blockIdx.x & 3;
  const int b = blockIdx.x >> 2;
  const int t = threadIdx.x;
  __shared__ short tile[128 * 128];
  if (sub < 2) {
    const float* __restrict__ base = pws + ((size_t)b * 2) * 4 * 32768;
    const int off = sub * 16384;
    for (int i = t; i < 16384; i += 256) {
      int ii = off + i;
      int k = ii >> 7;
      float v = base[ii] + base[ii + 32768] + base[ii + 65536] + base[ii + 98304] + Eb[k];
      kp[(size_t)b * 32768 + ii] = f2bf(v);
    }
  } else {
    const int kh = sub - 2;
    const float* __restrict__ base = pws + (((size_t)b * 2 + 1) * 4) * 32768 + kh * 16384;
    for (int i = t; i < 16384; i += 256) {
      int kl = i >> 7, d = i & 127;
      float v = base[i] + base[i + 32768] + base[i + 65536] + base[i + 98304] + Fb[kh * 128 + kl];
      tile[kl * 128 + (d ^ ((kl & 15) << 3))] = f2bf(v);
    }
    __syncthreads();
    for (int i = t; i < 16384; i += 256) {
      int d = i >> 7, kl = i & 127;
      vpt[(size_t)b * 32768 + d * 256 + kh * 128 + kl] = tile[kl * 128 + (d ^ ((kl & 15) << 3))];
    }
  }
}

// ---------------------------------------------------------------------------
// Stage 2: attention v4 (unchanged, verified). grid 256, 1024 thr,
// __launch_bounds__(1024,4), 160KB LDS, zero mid-loop barriers.
// ---------------------------------------------------------------------------
__global__ __launch_bounds__(1024, 4) void attn_kernel(
    const float* __restrict__ Q, const short* __restrict__ kp,
    const short* __restrict__ vpt, float* __restrict__ out) {
  const int bid = blockIdx.x;
  const int wk = (bid & 7) * 32 + (bid >> 3);  // XCD-chunked: 4 b's per XCD
  const int b = wk >> 3;
  const int slice = wk & 7;
  const int t = threadIdx.x;
  const int lane = t & 63;
  const int w = t >> 6;  // 0..15
  const int l15 = lane & 15, l4 = lane >> 4;

  __shared__ __align__(16) short lbuf[81920];
  short* lkp = lbuf;
  short* lvpt = lbuf + 32768;
  short* lpw = lbuf + 65536 + w * 1024;  // 2KB/wave

  const short* __restrict__ kpb = kp + (size_t)b * 32768;
  const short* __restrict__ vptb = vpt + (size_t)b * 32768;

#pragma unroll
  for (int i = 0; i < 4; ++i) {
    int g = t + i * 1024;
    int row = g >> 4, c = g & 15;
    __builtin_amdgcn_global_load_lds(
        (const __attribute__((address_space(1))) void*)(kpb + (size_t)row * 128 +
                                                        ((c ^ (row & 7)) << 3)),
        (__attribute__((address_space(3))) void*)(&lkp[g * 8]), 16, 0, 0);
  }
#pragma unroll
  for (int i = 0; i < 4; ++i) {
    int g = t + i * 1024;
    int row = g >> 5, c = g & 31;
    __builtin_amdgcn_global_load_lds(
        (const __attribute__((address_space(1))) void*)(vptb + (size_t)row * 256 +
                                                        ((c ^ (row & 7)) << 3)),
        (__attribute__((address_space(3))) void*)(&lvpt[g * 8]), 16, 0, 0);
  }

  const float scale = 0.08838834764831845f;  // 1/sqrt(128)
  f32x4 qraw[8];
  {
    const float* qr = Q + ((size_t)b * N_SEQ + slice * 512 + w * 16 + l15) * D_HEAD;
#pragma unroll
    for (int ks = 0; ks < 4; ++ks) {
      qraw[2 * ks] = *(const f32x4*)(qr + ks * 32 + l4 * 8);
      qraw[2 * ks + 1] = *(const f32x4*)(qr + ks * 32 + l4 * 8 + 4);
    }
  }
  asm volatile("s_waitcnt vmcnt(0)" ::: "memory");
  __syncthreads();

#pragma unroll
  for (int rd = 0; rd < 2; ++rd) {
    const int rowBase = slice * 512 + rd * 256 + w * 16;

    bf16x8 qf[4];
#pragma unroll
    for (int ks = 0; ks < 4; ++ks) {
      union { unsigned int u[4]; bf16x8 v; } cv;
      cv.u[0] = cvtpk(qraw[2 * ks][0] * scale, qraw[2 * ks][1] * scale);
      cv.u[1] = cvtpk(qraw[2 * ks][2] * scale, qraw[2 * ks][3] * scale);
      cv.u[2] = cvtpk(qraw[2 * ks + 1][0] * scale, qraw[2 * ks + 1][1] * scale);
      cv.u[3] = cvtpk(qraw[2 * ks + 1][2] * scale, qraw[2 * ks + 1][3] * scale);
      qf[ks] = cv.v;
    }

    f32x4 accs[16];
#pragma unroll
    for (int i = 0; i < 16; ++i) accs[i] = (f32x4){0.f, 0.f, 0.f, 0.f};
#pragma unroll
    for (int ks = 0; ks < 4; ++ks) {
#pragma unroll
      for (int nt = 0; nt < 16; ++nt) {
        bf16x8 af = *(const bf16x8*)(&lkp[(nt * 16 + l15) * 128 +
                                          (((ks * 4 + l4) ^ (l15 & 7)) << 3)]);
        accs[nt] = __builtin_amdgcn_mfma_f32_16x16x32_bf16(af, qf[ks], accs[nt], 0, 0, 0);
      }
    }

    float m = -1e30f;
#pragma unroll
    for (int nt = 0; nt < 16; ++nt)
#pragma unroll
      for (int r = 0; r < 4; ++r) m = fmaxf(m, accs[nt][r]);
    m = fmaxf(m, __shfl_xor(m, 16));
    m = fmaxf(m, __shfl_xor(m, 32));
    float s = 0.f;
#pragma unroll
    for (int nt = 0; nt < 16; ++nt)
#pragma unroll
      for (int r = 0; r < 4; ++r) {
        float e = __expf(accs[nt][r] - m);
        accs[nt][r] = e;
        s += e;
      }
    s += __shfl_xor(s, 16);
    s += __shfl_xor(s, 32);
    float inv = 1.0f / s;

    f32x4 acco[8];
#pragma unroll
    for (int i = 0; i < 8; ++i) acco[i] = (f32x4){0.f, 0.f, 0.f, 0.f};
#pragma unroll
    for (int qq = 0; qq < 4; ++qq) {
#pragma unroll
      for (int ntl = 0; ntl < 4; ++ntl) {
        int nt = qq * 4 + ntl;
        int cw = 2 * ntl + (l4 >> 1);
        unsigned int p0 = cvtpk(accs[nt][0] * inv, accs[nt][1] * inv);
        unsigned int p1 = cvtpk(accs[nt][2] * inv, accs[nt][3] * inv);
        *(u32x2*)((char*)lpw + l15 * 128 + ((cw ^ (l15 & 7)) << 4) + (l4 & 1) * 8) =
            (u32x2){p0, p1};
      }
      if (rd == 0 && qq == 3) {
        const float* qr = Q + ((size_t)b * N_SEQ + slice * 512 + 256 + w * 16 + l15) * D_HEAD;
#pragma unroll
        for (int ks = 0; ks < 4; ++ks) {
          qraw[2 * ks] = *(const f32x4*)(qr + ks * 32 + l4 * 8);
          qraw[2 * ks + 1] = *(const f32x4*)(qr + ks * 32 + l4 * 8 + 4);
        }
      }
#pragma unroll
      for (int ksl = 0; ksl < 2; ++ksl) {
        bf16x8 pa = *(const bf16x8*)((char*)lpw + l15 * 128 +
                                     (((4 * ksl + l4) ^ (l15 & 7)) << 4));
        int ksa = qq * 2 + ksl;
#pragma unroll
        for (int ntv = 0; ntv < 8; ++ntv) {
          bf16x8 av = *(const bf16x8*)(&lvpt[(ntv * 16 + l15) * 256 +
                                             (((ksa * 4 + l4) ^ (l15 & 7)) << 3)]);
          acco[ntv] = __builtin_amdgcn_mfma_f32_16x16x32_bf16(av, pa, acco[ntv], 0, 0, 0);
        }
      }
    }

    float* ob = out + ((size_t)b * N_SEQ + rowBase) * D_HEAD;
#pragma unroll
    for (int ntv = 0; ntv < 8; ++ntv)
      *(f32x4*)(ob + (size_t)l15 * D_HEAD + ntv * 16 + l4 * 4) = acco[ntv];
  }
}

// ---------------------------------------------------------------------------
extern "C" void kernel_launch(void* const* d_in, const int* in_sizes, int n_in,
                              void* d_out, int out_size, void* d_ws, size_t ws_size,
                              hipStream_t stream) {
  const float* Q  = (const float*)d_in[0];
  const float* K  = (const float*)d_in[1];
  const float* V  = (const float*)d_in[2];
  const float* EW = (const float*)d_in[3];
  const float* Eb = (const float*)d_in[4];
  const float* FW = (const float*)d_in[5];
  const float* Fb = (const float*)d_in[6];
  float* out = (float*)d_out;

  // d_out scratch (dead before attn writes): [0,4MB) wbf; [8MB,41.5MB) pws
  short* wbf = (short*)d_out;
  float* pws = (float*)d_out + 2097152;
  short* kpb = (short*)d_ws;
  short* vpt = (short*)((char*)d_ws + (size_t)32 * KP_DIM * D_HEAD * 2);

  conv_w_kernel<<<dim3(2048), dim3(256), 0, stream>>>(EW, FW, wbf);
  proj_partial_kernel<<<dim3(512), dim3(512), 0, stream>>>(K, V, wbf, pws);
  reduce_bias_kernel<<<dim3(128), dim3(256), 0, stream>>>(pws, Eb, Fb, kpb, vpt);
  attn_kernel<<<dim3(256), dim3(1024), 0, stream>>>(Q, kpb, vpt, out);
}

// Round 13
// 95.130 us; speedup vs baseline: 1.2024x; 1.0512x over previous
//
#include <hip/hip_runtime.h>
#include <cstdint>
#include <cstddef>

#define N_SEQ 4096
#define D_HEAD 128
#define KP_DIM 256

typedef __attribute__((ext_vector_type(4))) float f32x4;
typedef __attribute__((ext_vector_type(8))) short bf16x8;
typedef __attribute__((ext_vector_type(4))) short s16x4;
typedef __attribute__((ext_vector_type(2))) unsigned int u32x2;

static __device__ __forceinline__ short f2bf(float f) {
  uint32_t u = __builtin_bit_cast(uint32_t, f);
  u += 0x7FFFu + ((u >> 16) & 1u);
  return (short)(u >> 16);
}

static __device__ __forceinline__ unsigned int cvtpk(float a, float b) {
  unsigned int r;
  asm("v_cvt_pk_bf16_f32 %0, %1, %2" : "=v"(r) : "v"(a), "v"(b));
  return r;
}

static __device__ __forceinline__ int swz8(int r) { return (r ^ (r >> 2)) & 7; }

// ---------------------------------------------------------------------------
// Stage 0: convert E_W,F_W f32 -> bf16 wbf[2][256][4096] (d_out scratch)
// ---------------------------------------------------------------------------
__global__ __launch_bounds__(256) void conv_w_kernel(
    const float* __restrict__ EW, const float* __restrict__ FW,
    short* __restrict__ wbf) {
  const int idx = blockIdx.x * 256 + threadIdx.x;
  const int half = 262144;
  f32x4 v = (idx < half) ? *(const f32x4*)(EW + (size_t)idx * 4)
                         : *(const f32x4*)(FW + (size_t)(idx - half) * 4);
  u32x2 h = {cvtpk(v[0], v[1]), cvtpk(v[2], v[3])};
  *(u32x2*)(wbf + (size_t)idx * 4) = h;
}

// ---------------------------------------------------------------------------
// Stage 1 (v7): partial projections. grid 256 (1 block/CU, XCD-chunked),
// 1024 thr = 16 waves (8k x 2d of 32x64). Block = (b,p,s): full 256 k x 128 d
// over n-chunk s*1024 (16 iters BK=64). X f32 streamed ONCE per CU. LDS 96KB:
// W[256][64]bf16 x2 (global_load_lds, pre-swizzled src) + X^T[128][64] x2
// (depth-2 reg prefetch + cvt_pk). Counted vmcnt, never 0 mid-loop.
// pws[b][p][s][k 256][d 128] f32 partials.
// ---------------------------------------------------------------------------
__global__ __launch_bounds__(1024, 4) void proj_partial_kernel(
    const float* __restrict__ Kin, const float* __restrict__ Vin,
    const short* __restrict__ wbf, float* __restrict__ pws) {
  const int bid = blockIdx.x;                  // 0..255
  const int wk = (bid & 7) * 32 + (bid >> 3);  // XCD x owns wk [32x, 32x+32)
  const int b = wk & 31;
  const int s = (wk >> 5) & 3;
  const int p = wk >> 7;

  const float* __restrict__ X = (p == 0 ? Kin : Vin) + (size_t)b * (N_SEQ * D_HEAD);
  const short* __restrict__ wp = wbf + (size_t)p * (KP_DIM * N_SEQ);
  float* __restrict__ outp = pws + ((((size_t)b * 2 + p) * 4) + s) * (KP_DIM * D_HEAD);

  __shared__ __align__(16) short lw[2][KP_DIM * 64];  // 32KB x2: W [256 k][64 n]
  __shared__ __align__(16) short xt[2][D_HEAD * 64];  // 16KB x2: X^T [128 d][64 n]

  const int t = threadIdx.x;
  const int lane = t & 63;
  const int w = t >> 6;            // 0..15
  const int wkk = (w >> 1) * 32;   // wave k offset (8 groups of 32)
  const int wdd = (w & 1) * 64;    // wave d offset (2 groups of 64)
  const int l15 = lane & 15;
  const int l4 = lane >> 4;
  const int dq = t & 31;           // d-quad for X staging (0..31)
  const int ng = t >> 5;           // n-pair group (0..31) for X staging

  const int n0 = s * 1024;

  f32x4 acc[2][4];
#pragma unroll
  for (int i = 0; i < 2; ++i)
#pragma unroll
    for (int j = 0; j < 4; ++j) acc[i][j] = (f32x4){0.f, 0.f, 0.f, 0.f};

  f32x4 xA[2], xB[2];  // depth-2 X prefetch: 2 n-rows per thread

#define PROJ_WISSUE(BUF, NC)                                                        \
  do {                                                                              \
    _Pragma("unroll") for (int i_ = 0; i_ < 2; ++i_) {                              \
      int g_ = t + i_ * 1024;                                                       \
      int row_ = g_ >> 3, c_ = g_ & 7;                                              \
      __builtin_amdgcn_global_load_lds(                                             \
          (const __attribute__((address_space(1))) void*)(wp + (size_t)row_ * N_SEQ \
              + (NC) + ((c_ ^ swz8(row_)) << 3)),                                   \
          (__attribute__((address_space(3))) void*)(&lw[BUF][g_ * 8]), 16, 0, 0);   \
    }                                                                               \
  } while (0)

#define PROJ_XISSUE(XR, NC)                                                         \
  do {                                                                              \
    _Pragma("unroll") for (int i_ = 0; i_ < 2; ++i_)                                \
      XR[i_] = *(const f32x4*)(X + (size_t)((NC) + ng * 2 + i_) * D_HEAD + dq * 4); \
  } while (0)

#define PROJ_XCVT(XR, BUF)                                                          \
  do {                                                                              \
    _Pragma("unroll") for (int j_ = 0; j_ < 4; ++j_) {                              \
      int drow_ = dq * 4 + j_;                                                      \
      unsigned int hv_ = cvtpk(XR[0][j_], XR[1][j_]);                               \
      *(unsigned int*)(&xt[BUF][drow_ * 64 + ((ng * 2) ^ (swz8(drow_) << 3))]) = hv_; \
    }                                                                               \
  } while (0)

#define PROJ_COMPUTE(CUR)                                                           \
  do {                                                                              \
    _Pragma("unroll") for (int ks2 = 0; ks2 < 2; ++ks2) {                           \
      const int col0 = ks2 * 32 + l4 * 8;                                           \
      bf16x8 a_[2], bb_[4];                                                         \
      _Pragma("unroll") for (int mt = 0; mt < 2; ++mt) {                            \
        int row_ = wkk + mt * 16 + l15;                                             \
        a_[mt] = *(const bf16x8*)(&lw[CUR][row_ * 64 + (col0 ^ (swz8(row_) << 3))]); \
      }                                                                             \
      _Pragma("unroll") for (int nt = 0; nt < 4; ++nt) {                            \
        int row_ = wdd + nt * 16 + l15;                                             \
        bb_[nt] = *(const bf16x8*)(&xt[CUR][row_ * 64 + (col0 ^ (swz8(row_) << 3))]); \
      }                                                                             \
      _Pragma("unroll") for (int mt = 0; mt < 2; ++mt)                              \
        _Pragma("unroll") for (int nt = 0; nt < 4; ++nt)                            \
          acc[mt][nt] = __builtin_amdgcn_mfma_f32_16x16x32_bf16(a_[mt], bb_[nt],    \
                                                                acc[mt][nt], 0, 0, 0); \
    }                                                                               \
  } while (0)

  // ---- prologue ----
  PROJ_XISSUE(xA, n0);                                   // X(0): +2
  PROJ_WISSUE(0, n0);                                    // W(0): +2
  asm volatile("s_waitcnt vmcnt(2)" ::: "memory");       // X(0) done
  PROJ_XCVT(xA, 0);
  PROJ_XISSUE(xB, n0 + 64);                              // X(1): +2
  asm volatile("s_waitcnt vmcnt(2)" ::: "memory");       // W(0) done, X(1) flies
  __syncthreads();

  // ---- main loop: iters 0..13 as 7 even/odd pairs ----
  for (int itp = 0; itp < 7; ++itp) {
    const int it0 = itp * 2;
    // even iter (cur=0)
    PROJ_WISSUE(1, n0 + (it0 + 1) * 64);                 // W(it+1): +2
    PROJ_XISSUE(xA, n0 + (it0 + 2) * 64);                // X(it+2): +2
    PROJ_COMPUTE(0);
    asm volatile("s_waitcnt vmcnt(4)" ::: "memory");     // X(it+1) done
    PROJ_XCVT(xB, 1);
    asm volatile("s_waitcnt vmcnt(2)" ::: "memory");     // W(it+1) done
    __syncthreads();
    // odd iter (cur=1)
    PROJ_WISSUE(0, n0 + (it0 + 2) * 64);
    PROJ_XISSUE(xB, n0 + (it0 + 3) * 64);
    PROJ_COMPUTE(1);
    asm volatile("s_waitcnt vmcnt(4)" ::: "memory");
    PROJ_XCVT(xA, 0);
    asm volatile("s_waitcnt vmcnt(2)" ::: "memory");
    __syncthreads();
  }
  // ---- it=14 (cur=0) ----
  PROJ_WISSUE(1, n0 + 15 * 64);                          // W(15): +2
  PROJ_COMPUTE(0);
  asm volatile("s_waitcnt vmcnt(2)" ::: "memory");       // X(15) done
  PROJ_XCVT(xB, 1);
  asm volatile("s_waitcnt vmcnt(0)" ::: "memory");       // W(15) done
  __syncthreads();
  // ---- it=15 (cur=1) ----
  PROJ_COMPUTE(1);

#undef PROJ_WISSUE
#undef PROJ_XISSUE
#undef PROJ_XCVT
#undef PROJ_COMPUTE

  // ---- write f32 partials ----
#pragma unroll
  for (int mt = 0; mt < 2; ++mt)
#pragma unroll
    for (int nt = 0; nt < 4; ++nt)
#pragma unroll
      for (int r = 0; r < 4; ++r) {
        int kk = wkk + mt * 16 + l4 * 4 + r;
        int dd = wdd + nt * 16 + l15;
        outp[kk * D_HEAD + dd] = acc[mt][nt][r];
      }
}

// ---------------------------------------------------------------------------
// Stage 1b: reduce 4 partials + bias. grid 128 (unchanged).
// ---------------------------------------------------------------------------
__global__ __launch_bounds__(256) void reduce_bias_kernel(
    const float* __restrict__ pws, const float* __restrict__ Eb,
    const float* __restrict__ Fb, short* __restrict__ kp, short* __restrict__ vpt) {
  const int sub = blockIdx.x & 3;
  const int b = blockIdx.x >> 2;
  const int t = threadIdx.x;
  __shared__ short tile[128 * 128];
  if (sub < 2) {
    const float* __restrict__ base = pws + ((size_t)b * 2) * 4 * 32768;
    const int off = sub * 16384;
    for (int i = t; i < 16384; i += 256) {
      int ii = off + i;
      int k = ii >> 7;
      float v = base[ii] + base[ii + 32768] + base[ii + 65536] + base[ii + 98304] + Eb[k];
      kp[(size_t)b * 32768 + ii] = f2bf(v);
    }
  } else {
    const int kh = sub - 2;
    const float* __restrict__ base = pws + (((size_t)b * 2 + 1) * 4) * 32768 + kh * 16384;
    for (int i = t; i < 16384; i += 256) {
      int kl = i >> 7, d = i & 127;
      float v = base[i] + base[i + 32768] + base[i + 65536] + base[i + 98304] + Fb[kh * 128 + kl];
      tile[kl * 128 + (d ^ ((kl & 15) << 3))] = f2bf(v);
    }
    __syncthreads();
    for (int i = t; i < 16384; i += 256) {
      int d = i >> 7, kl = i & 127;
      vpt[(size_t)b * 32768 + d * 256 + kh * 128 + kl] = tile[kl * 128 + (d ^ ((kl & 15) << 3))];
    }
  }
}

// ---------------------------------------------------------------------------
// Stage 2: attention v4 (unchanged, verified). grid 256, 1024 thr,
// __launch_bounds__(1024,4), 160KB LDS, zero mid-loop barriers.
// ---------------------------------------------------------------------------
__global__ __launch_bounds__(1024, 4) void attn_kernel(
    const float* __restrict__ Q, const short* __restrict__ kp,
    const short* __restrict__ vpt, float* __restrict__ out) {
  const int bid = blockIdx.x;
  const int wk = (bid & 7) * 32 + (bid >> 3);  // XCD-chunked: 4 b's per XCD
  const int b = wk >> 3;
  const int slice = wk & 7;
  const int t = threadIdx.x;
  const int lane = t & 63;
  const int w = t >> 6;  // 0..15
  const int l15 = lane & 15, l4 = lane >> 4;

  __shared__ __align__(16) short lbuf[81920];
  short* lkp = lbuf;
  short* lvpt = lbuf + 32768;
  short* lpw = lbuf + 65536 + w * 1024;  // 2KB/wave

  const short* __restrict__ kpb = kp + (size_t)b * 32768;
  const short* __restrict__ vptb = vpt + (size_t)b * 32768;

#pragma unroll
  for (int i = 0; i < 4; ++i) {
    int g = t + i * 1024;
    int row = g >> 4, c = g & 15;
    __builtin_amdgcn_global_load_lds(
        (const __attribute__((address_space(1))) void*)(kpb + (size_t)row * 128 +
                                                        ((c ^ (row & 7)) << 3)),
        (__attribute__((address_space(3))) void*)(&lkp[g * 8]), 16, 0, 0);
  }
#pragma unroll
  for (int i = 0; i < 4; ++i) {
    int g = t + i * 1024;
    int row = g >> 5, c = g & 31;
    __builtin_amdgcn_global_load_lds(
        (const __attribute__((address_space(1))) void*)(vptb + (size_t)row * 256 +
                                                        ((c ^ (row & 7)) << 3)),
        (__attribute__((address_space(3))) void*)(&lvpt[g * 8]), 16, 0, 0);
  }

  const float scale = 0.08838834764831845f;  // 1/sqrt(128)
  f32x4 qraw[8];
  {
    const float* qr = Q + ((size_t)b * N_SEQ + slice * 512 + w * 16 + l15) * D_HEAD;
#pragma unroll
    for (int ks = 0; ks < 4; ++ks) {
      qraw[2 * ks] = *(const f32x4*)(qr + ks * 32 + l4 * 8);
      qraw[2 * ks + 1] = *(const f32x4*)(qr + ks * 32 + l4 * 8 + 4);
    }
  }
  asm volatile("s_waitcnt vmcnt(0)" ::: "memory");
  __syncthreads();

#pragma unroll
  for (int rd = 0; rd < 2; ++rd) {
    const int rowBase = slice * 512 + rd * 256 + w * 16;

    bf16x8 qf[4];
#pragma unroll
    for (int ks = 0; ks < 4; ++ks) {
      union { unsigned int u[4]; bf16x8 v; } cv;
      cv.u[0] = cvtpk(qraw[2 * ks][0] * scale, qraw[2 * ks][1] * scale);
      cv.u[1] = cvtpk(qraw[2 * ks][2] * scale, qraw[2 * ks][3] * scale);
      cv.u[2] = cvtpk(qraw[2 * ks + 1][0] * scale, qraw[2 * ks + 1][1] * scale);
      cv.u[3] = cvtpk(qraw[2 * ks + 1][2] * scale, qraw[2 * ks + 1][3] * scale);
      qf[ks] = cv.v;
    }

    f32x4 accs[16];
#pragma unroll
    for (int i = 0; i < 16; ++i) accs[i] = (f32x4){0.f, 0.f, 0.f, 0.f};
#pragma unroll
    for (int ks = 0; ks < 4; ++ks) {
#pragma unroll
      for (int nt = 0; nt < 16; ++nt) {
        bf16x8 af = *(const bf16x8*)(&lkp[(nt * 16 + l15) * 128 +
                                          (((ks * 4 + l4) ^ (l15 & 7)) << 3)]);
        accs[nt] = __builtin_amdgcn_mfma_f32_16x16x32_bf16(af, qf[ks], accs[nt], 0, 0, 0);
      }
    }

    float m = -1e30f;
#pragma unroll
    for (int nt = 0; nt < 16; ++nt)
#pragma unroll
      for (int r = 0; r < 4; ++r) m = fmaxf(m, accs[nt][r]);
    m = fmaxf(m, __shfl_xor(m, 16));
    m = fmaxf(m, __shfl_xor(m, 32));
    float s = 0.f;
#pragma unroll
    for (int nt = 0; nt < 16; ++nt)
#pragma unroll
      for (int r = 0; r < 4; ++r) {
        float e = __expf(accs[nt][r] - m);
        accs[nt][r] = e;
        s += e;
      }
    s += __shfl_xor(s, 16);
    s += __shfl_xor(s, 32);
    float inv = 1.0f / s;

    f32x4 acco[8];
#pragma unroll
    for (int i = 0; i < 8; ++i) acco[i] = (f32x4){0.f, 0.f, 0.f, 0.f};
#pragma unroll
    for (int qq = 0; qq < 4; ++qq) {
#pragma unroll
      for (int ntl = 0; ntl < 4; ++ntl) {
        int nt = qq * 4 + ntl;
        int cw = 2 * ntl + (l4 >> 1);
        unsigned int p0 = cvtpk(accs[nt][0] * inv, accs[nt][1] * inv);
        unsigned int p1 = cvtpk(accs[nt][2] * inv, accs[nt][3] * inv);
        *(u32x2*)((char*)lpw + l15 * 128 + ((cw ^ (l15 & 7)) << 4) + (l4 & 1) * 8) =
            (u32x2){p0, p1};
      }
      if (rd == 0 && qq == 3) {
        const float* qr = Q + ((size_t)b * N_SEQ + slice * 512 + 256 + w * 16 + l15) * D_HEAD;
#pragma unroll
        for (int ks = 0; ks < 4; ++ks) {
          qraw[2 * ks] = *(const f32x4*)(qr + ks * 32 + l4 * 8);
          qraw[2 * ks + 1] = *(const f32x4*)(qr + ks * 32 + l4 * 8 + 4);
        }
      }
#pragma unroll
      for (int ksl = 0; ksl < 2; ++ksl) {
        bf16x8 pa = *(const bf16x8*)((char*)lpw + l15 * 128 +
                                     (((4 * ksl + l4) ^ (l15 & 7)) << 4));
        int ksa = qq * 2 + ksl;
#pragma unroll
        for (int ntv = 0; ntv < 8; ++ntv) {
          bf16x8 av = *(const bf16x8*)(&lvpt[(ntv * 16 + l15) * 256 +
                                             (((ksa * 4 + l4) ^ (l15 & 7)) << 3)]);
          acco[ntv] = __builtin_amdgcn_mfma_f32_16x16x32_bf16(av, pa, acco[ntv], 0, 0, 0);
        }
      }
    }

    float* ob = out + ((size_t)b * N_SEQ + rowBase) * D_HEAD;
#pragma unroll
    for (int ntv = 0; ntv < 8; ++ntv)
      *(f32x4*)(ob + (size_t)l15 * D_HEAD + ntv * 16 + l4 * 4) = acco[ntv];
  }
}

// ---------------------------------------------------------------------------
extern "C" void kernel_launch(void* const* d_in, const int* in_sizes, int n_in,
                              void* d_out, int out_size, void* d_ws, size_t ws_size,
                              hipStream_t stream) {
  const float* Q  = (const float*)d_in[0];
  const float* K  = (const float*)d_in[1];
  const float* V  = (const float*)d_in[2];
  const float* EW = (const float*)d_in[3];
  const float* Eb = (const float*)d_in[4];
  const float* FW = (const float*)d_in[5];
  const float* Fb = (const float*)d_in[6];
  float* out = (float*)d_out;

  // d_out scratch (dead before attn writes): [0,4MB) wbf; [8MB,41.5MB) pws
  short* wbf = (short*)d_out;
  float* pws = (float*)d_out + 2097152;
  short* kpb = (short*)d_ws;
  short* vpt = (short*)((char*)d_ws + (size_t)32 * KP_DIM * D_HEAD * 2);

  conv_w_kernel<<<dim3(2048), dim3(256), 0, stream>>>(EW, FW, wbf);
  proj_partial_kernel<<<dim3(256), dim3(1024), 0, stream>>>(K, V, wbf, pws);
  reduce_bias_kernel<<<dim3(128), dim3(256), 0, stream>>>(pws, Eb, Fb, kpb, vpt);
  attn_kernel<<<dim3(256), dim3(1024), 0, stream>>>(Q, kpb, vpt, out);
}